// Round 7
// baseline (72.765 us; speedup 1.0000x reference)
//
#include <hip/hip_runtime.h>

namespace {
constexpr int BATCH = 512;
constexpr int SEQL  = 512;
constexpr int HID   = 256;
constexpr int MORPH = 24;
constexpr float NEGV = -1.0e9f;
}

__device__ __forceinline__ unsigned okey(float f) {
    unsigned u = __float_as_uint(f);
    return u ^ (unsigned)(((int)u >> 31) | 0x80000000);
}

// ---- Kernel A: order-keys for all (b,l). grid 4096: blk=(b<<3)|q, rows [64q,64q+64).
// 256 thr = 4 waves, wave-per-row float4 matvec + shuffle reduce. Balanced, HBM-bound.
extern "C" __global__ __launch_bounds__(256)
void k_scores(const float* __restrict__ we, const int* __restrict__ wlen,
              const float* __restrict__ Wv, const float* __restrict__ bias,
              unsigned* __restrict__ keys)
{
    const int blk = blockIdx.x;
    const int b = blk >> 3, q = blk & 7;
    const int tid = threadIdx.x, lane = tid & 63, wave = tid >> 6;
    const int nvalid = wlen[b] - 1;
    const float b0 = bias[0];
    const float* __restrict__ werow = we + (size_t)b * (SEQL * HID);
    const unsigned KEYNEG = okey(NEGV);
    const float4 w4 = reinterpret_cast<const float4*>(Wv)[lane];
    const int rs = q * 64;

    for (int l = rs + wave; l < rs + 64; l += 4) {
        unsigned kk = KEYNEG;
        if (l < nvalid) {                       // wave-uniform
            const float4 v = reinterpret_cast<const float4*>(werow + (size_t)l * HID)[lane];
            float p = v.x * w4.x + v.y * w4.y + v.z * w4.z + v.w * w4.w;
            #pragma unroll
            for (int off = 32; off >= 1; off >>= 1)
                p += __shfl_xor(p, off, 64);
            kk = okey(p + b0);
        }
        if (lane == 0) keys[b * SEQL + l] = kk;
    }
}

// ---- Kernel B: per-b radix select -> sep list (ws) + bpm. 512 blocks x 512 thr.
extern "C" __global__ __launch_bounds__(512)
void k_select(const unsigned* __restrict__ keys, const int* __restrict__ wlen,
              const int* __restrict__ nmorph, int* __restrict__ sep_g,
              float* __restrict__ out)
{
    const int b = blockIdx.x;
    const int tid = threadIdx.x, lane = tid & 63, wave = tid >> 6;

    __shared__ unsigned s_keys[SEQL];
    __shared__ int s_hist[256];
    __shared__ int s_c2m[SEQL];
    __shared__ unsigned long long s_eqm[8], s_ind[8];
    __shared__ unsigned s_p, s_T;
    __shared__ int s_Kr, s_KrF, s_done;

    const int wl = wlen[b];
    const int nm = nmorph[b];
    const int K  = nm - 1;

    s_keys[tid] = keys[b * SEQL + tid];
    if (tid == 0) { s_p = 0u; s_Kr = K; s_done = 0; }
    __syncthreads();

    int done = 0;
    for (int pass = 0; pass < 4 && !done; ++pass) {
        const int shift = 24 - 8 * pass;
        if (tid < 256) s_hist[tid] = 0;
        __syncthreads();
        {
            const unsigned k = s_keys[tid];
            if (pass == 0 || (k >> (shift + 8)) == (s_p >> (shift + 8)))
                atomicAdd(&s_hist[(k >> shift) & 255], 1);
        }
        __syncthreads();
        if (wave == 0) {
            const int v0 = lane * 4;
            const int h0 = s_hist[v0], h1 = s_hist[v0 + 1];
            const int h2 = s_hist[v0 + 2], h3 = s_hist[v0 + 3];
            const int local = h0 + h1 + h2 + h3;
            int T = local;
            #pragma unroll
            for (int off = 1; off < 64; off <<= 1) {
                const int u = __shfl_down(T, off, 64);
                if (lane + off < 64) T += u;
            }
            const int A  = T - local;
            const int S3 = A + h3, S2 = S3 + h2, S1 = S2 + h1, S0 = S1 + h0;
            const int Kr = s_Kr;
            const unsigned p = s_p;
            int v = -1, Sv = 0, Sv1 = 0;
            if (A  < Kr && Kr <= S3) { v = v0 + 3; Sv = S3; Sv1 = A;  }
            if (S3 < Kr && Kr <= S2) { v = v0 + 2; Sv = S2; Sv1 = S3; }
            if (S2 < Kr && Kr <= S1) { v = v0 + 1; Sv = S1; Sv1 = S2; }
            if (S1 < Kr && Kr <= S0) { v = v0 + 0; Sv = S0; Sv1 = S1; }
            if (v >= 0) {
                const unsigned pv = p | ((unsigned)v << shift);
                if (Sv == Kr)        { s_T = pv - 1u; s_KrF = 0;        s_done = 1; }
                else if (shift == 0) { s_T = pv;      s_KrF = Kr - Sv1; s_done = 1; }
                else                 { s_p = pv;      s_Kr = Kr - Sv1; }
            }
        }
        __syncthreads();
        done = s_done;
    }

    const unsigned Tf = s_T;
    const int KrF = s_KrF;
    const unsigned k = s_keys[tid];
    const bool gt = (k > Tf);
    const bool eq = (k == Tf);
    const unsigned long long eb = __ballot(eq);
    if (lane == 0) s_eqm[wave] = eb;
    __syncthreads();

    auto prefix8 = [&](const unsigned long long* w8, int pos) -> int {
        const int wi = pos >> 6;
        const unsigned long long lowmask = (1ull << (pos & 63)) - 1ull;
        int r = 0;
        #pragma unroll
        for (int q2 = 0; q2 < 8; ++q2) {
            const unsigned long long w = w8[q2];
            r += (q2 < wi) ? __popcll(w) : ((q2 == wi) ? __popcll(w & lowmask) : 0);
        }
        return r;
    };

    const int f = gt || (eq && prefix8(s_eqm, tid) < KrF);
    const unsigned long long fb = __ballot(f);
    if (lane == 0) s_ind[wave] = fb;
    __syncthreads();
    {
        const int cnt = prefix8(s_ind, tid);
        s_c2m[tid] = cnt;
        if (f) sep_g[b * 32 + cnt] = tid;   // cnt in [0,K): unique
    }
    __syncthreads();

    // bpm one-hot, float4 (6 per l-row)
    float* __restrict__ bpm = out + (size_t)BATCH * MORPH * HID + (size_t)b * (SEQL * MORPH);
    for (int v = tid; v < SEQL * MORPH / 4; v += 512) {
        const int l  = v / 6;
        const int qv = v - l * 6;
        const int c  = s_c2m[l];
        const int mb = qv * 4;
        const bool valid = (l < wl);
        float4 o;
        o.x = (valid && c == mb + 0 && mb + 0 < nm) ? 1.0f : 0.0f;
        o.y = (valid && c == mb + 1 && mb + 1 < nm) ? 1.0f : 0.0f;
        o.z = (valid && c == mb + 2 && mb + 2 < nm) ? 1.0f : 0.0f;
        o.w = (valid && c == mb + 3 && mb + 3 < nm) ? 1.0f : 0.0f;
        reinterpret_cast<float4*>(bpm)[v] = o;
    }
}

// ---- Kernel C: menc. grid 3072: blk = b*6 + g; wave-per-morpheme m = g*4+wave.
// Exclusive morpheme ownership -> plain stores, no atomics, no zero pass.
// Avg block work ~44 rows regardless of wl; 6x residency -> backfill balance.
extern "C" __global__ __launch_bounds__(256)
void k_menc(const float* __restrict__ we, const int* __restrict__ wlen,
            const int* __restrict__ nmorph, const int* __restrict__ sep_g,
            float* __restrict__ out)
{
    const int blk = blockIdx.x;
    const int b = blk / 6, g = blk - b * 6;
    const int tid = threadIdx.x, lane = tid & 63, wave = tid >> 6;
    const int m = g * 4 + wave;                 // 0..23
    const int wl = wlen[b], nm = nmorph[b], K = nm - 1;

    float4 a0 = {0,0,0,0}, a1 = {0,0,0,0}, a2 = {0,0,0,0}, a3 = {0,0,0,0};
    if (m < nm) {
        const int lo = (m == 0) ? 0 : sep_g[b * 32 + m - 1] + 1;
        const int hi = (m < K) ? sep_g[b * 32 + m] : wl - 1;   // inclusive
        const float* __restrict__ werow = we + (size_t)b * (SEQL * HID);
        int l = lo;
        for (; l + 3 <= hi; l += 4) {
            const float4 v0 = reinterpret_cast<const float4*>(werow + (size_t)(l    ) * HID)[lane];
            const float4 v1 = reinterpret_cast<const float4*>(werow + (size_t)(l + 1) * HID)[lane];
            const float4 v2 = reinterpret_cast<const float4*>(werow + (size_t)(l + 2) * HID)[lane];
            const float4 v3 = reinterpret_cast<const float4*>(werow + (size_t)(l + 3) * HID)[lane];
            a0.x += v0.x; a0.y += v0.y; a0.z += v0.z; a0.w += v0.w;
            a1.x += v1.x; a1.y += v1.y; a1.z += v1.z; a1.w += v1.w;
            a2.x += v2.x; a2.y += v2.y; a2.z += v2.z; a2.w += v2.w;
            a3.x += v3.x; a3.y += v3.y; a3.z += v3.z; a3.w += v3.w;
        }
        for (; l <= hi; ++l) {
            const float4 v0 = reinterpret_cast<const float4*>(werow + (size_t)l * HID)[lane];
            a0.x += v0.x; a0.y += v0.y; a0.z += v0.z; a0.w += v0.w;
        }
    }
    float4 t;
    t.x = (a0.x + a1.x) + (a2.x + a3.x);
    t.y = (a0.y + a1.y) + (a2.y + a3.y);
    t.z = (a0.z + a1.z) + (a2.z + a3.z);
    t.w = (a0.w + a1.w) + (a2.w + a3.w);
    if (m < MORPH)
        reinterpret_cast<float4*>(out + (size_t)b * (MORPH * HID) + (size_t)m * HID)[lane] = t;
}

extern "C" void kernel_launch(void* const* d_in, const int* in_sizes, int n_in,
                              void* d_out, int out_size, void* d_ws, size_t ws_size,
                              hipStream_t stream) {
    const float* we     = (const float*)d_in[0];
    const int*   wlen   = (const int*)d_in[1];
    const int*   nmorph = (const int*)d_in[2];
    const float* Wv     = (const float*)d_in[3];
    const float* bias   = (const float*)d_in[4];
    float* out = (float*)d_out;

    unsigned* keys = (unsigned*)d_ws;                       // 1 MB
    int*      sep  = (int*)((char*)d_ws + (1u << 20));      // 64 KB

    k_scores<<<dim3(BATCH * 8), dim3(256), 0, stream>>>(we, wlen, Wv, bias, keys);
    k_select<<<dim3(BATCH), dim3(512), 0, stream>>>(keys, wlen, nmorph, sep, out);
    k_menc  <<<dim3(BATCH * 6), dim3(256), 0, stream>>>(we, wlen, nmorph, sep, out);
}

// Round 8
// 64.252 us; speedup vs baseline: 1.1325x; 1.1325x over previous
//
#include <hip/hip_runtime.h>

namespace {
constexpr int BATCH = 512;
constexpr int SEQL  = 512;
constexpr int HID   = 256;
constexpr int MORPH = 24;
constexpr float NEGV = -1.0e9f;
constexpr int NTHR  = 1024;
}

typedef float f4v __attribute__((ext_vector_type(4)));

__device__ __forceinline__ unsigned okey(float f) {
    unsigned u = __float_as_uint(f);
    return u ^ (unsigned)(((int)u >> 31) | 0x80000000);
}

// One block per batch row b. 1024 threads = 16 waves, 2 blocks/CU.
// P1: scores->keys, 4 rows/wave/iter (4x16 lane split, 4-step reduce)
// P2: radix select (MSB-first, early exit) -> stable top-(nm-1) flags -> c2m
// P3/P4 concurrent: waves 12-15 write bpm (NT), waves 0-11 accumulate menc
extern "C" __global__ __launch_bounds__(NTHR, 8)
void morphseg_kernel(const float* __restrict__ we,    // [B, L, H]
                     const int*   __restrict__ wlen,  // [B]
                     const int*   __restrict__ nmorph,// [B]
                     const float* __restrict__ Wv,    // [H]
                     const float* __restrict__ bias,  // [1]
                     float* __restrict__ out)         // menc [B*M*H] then bpm [B*L*M]
{
    const int b    = blockIdx.x;
    const int tid  = threadIdx.x;
    const int lane = tid & 63;
    const int wave = tid >> 6;

    __shared__ unsigned s_keys[SEQL];                // 2 KB
    __shared__ int s_hist[256];                      // 1 KB
    __shared__ int s_c2m[SEQL];                      // 2 KB
    __shared__ float s_acc[MORPH][HID];              // 24 KB
    __shared__ unsigned long long s_eqm[8], s_ind[8];
    __shared__ unsigned s_p, s_T;
    __shared__ int s_Kr, s_KrF, s_done;

    const int wl = wlen[b];
    const int nm = nmorph[b];
    const int K  = nm - 1;
    const float b0 = bias[0];
    const float* __restrict__ werow = we + (size_t)b * (SEQL * HID);
    const unsigned KEYNEG = okey(NEGV);

    // ---- init
    if (tid < SEQL) s_keys[tid] = KEYNEG;
    {
        float* af = &s_acc[0][0];
        for (int i = tid; i < MORPH * HID; i += NTHR) af[i] = 0.0f;
    }
    if (tid == 0) { s_p = 0u; s_Kr = K; s_done = 0; }
    __syncthreads();

    // ---- Phase 1: keys. 4 rows per wave per iter; lane = 16*rg + hg.
    {
        const int hg = lane & 15;          // h-slice: floats [hg*16, hg*16+16)
        const int rg = lane >> 4;          // row within the 4-row group
        const float4* __restrict__ W4 = reinterpret_cast<const float4*>(Wv);
        const float4 w0 = W4[hg * 4 + 0], w1 = W4[hg * 4 + 1];
        const float4 w2 = W4[hg * 4 + 2], w3 = W4[hg * 4 + 3];
        const int nvalid = wl - 1;
        for (int l0 = wave * 4; l0 < nvalid; l0 += 64) {
            const int row = l0 + rg;
            if (row < nvalid) {            // uniform per 16-lane group
                const float4* __restrict__ rp =
                    reinterpret_cast<const float4*>(werow + (size_t)row * HID);
                const float4 v0 = rp[hg * 4 + 0], v1 = rp[hg * 4 + 1];
                const float4 v2 = rp[hg * 4 + 2], v3 = rp[hg * 4 + 3];
                float d = v0.x * w0.x; d = fmaf(v0.y, w0.y, d);
                d = fmaf(v0.z, w0.z, d); d = fmaf(v0.w, w0.w, d);
                d = fmaf(v1.x, w1.x, d); d = fmaf(v1.y, w1.y, d);
                d = fmaf(v1.z, w1.z, d); d = fmaf(v1.w, w1.w, d);
                d = fmaf(v2.x, w2.x, d); d = fmaf(v2.y, w2.y, d);
                d = fmaf(v2.z, w2.z, d); d = fmaf(v2.w, w2.w, d);
                d = fmaf(v3.x, w3.x, d); d = fmaf(v3.y, w3.y, d);
                d = fmaf(v3.z, w3.z, d); d = fmaf(v3.w, w3.w, d);
                #pragma unroll
                for (int off = 1; off < 16; off <<= 1)
                    d += __shfl_xor(d, off, 64);
                if (hg == 0) s_keys[row] = okey(d + b0);
            }
        }
    }
    __syncthreads();

    // ---- Phase 2: radix select, MSB-first, early exit on exact boundary
    int done = 0;
    for (int pass = 0; pass < 4 && !done; ++pass) {
        const int shift = 24 - 8 * pass;
        if (tid < 256) s_hist[tid] = 0;
        __syncthreads();
        if (tid < SEQL) {
            const unsigned k = s_keys[tid];
            if (pass == 0 || (k >> (shift + 8)) == (s_p >> (shift + 8)))
                atomicAdd(&s_hist[(k >> shift) & 255], 1);
        }
        __syncthreads();
        if (wave == 0) {
            const int v0 = lane * 4;
            const int h0 = s_hist[v0], h1 = s_hist[v0 + 1];
            const int h2 = s_hist[v0 + 2], h3 = s_hist[v0 + 3];
            const int local = h0 + h1 + h2 + h3;
            int T = local;
            #pragma unroll
            for (int off = 1; off < 64; off <<= 1) {
                const int u = __shfl_down(T, off, 64);
                if (lane + off < 64) T += u;
            }
            const int A  = T - local;
            const int S3 = A + h3, S2 = S3 + h2, S1 = S2 + h1, S0 = S1 + h0;
            const int Kr = s_Kr;
            const unsigned p = s_p;
            int v = -1, Sv = 0, Sv1 = 0;
            if (A  < Kr && Kr <= S3) { v = v0 + 3; Sv = S3; Sv1 = A;  }
            if (S3 < Kr && Kr <= S2) { v = v0 + 2; Sv = S2; Sv1 = S3; }
            if (S2 < Kr && Kr <= S1) { v = v0 + 1; Sv = S1; Sv1 = S2; }
            if (S1 < Kr && Kr <= S0) { v = v0 + 0; Sv = S0; Sv1 = S1; }
            if (v >= 0) {
                const unsigned pv = p | ((unsigned)v << shift);
                if (Sv == Kr)        { s_T = pv - 1u; s_KrF = 0;        s_done = 1; }
                else if (shift == 0) { s_T = pv;      s_KrF = Kr - Sv1; s_done = 1; }
                else                 { s_p = pv;      s_Kr = Kr - Sv1; }
            }
        }
        __syncthreads();
        done = s_done;
    }

    // ---- separator flags (stable ties) -> c2m
    const unsigned Tf = s_T;
    const int KrF = s_KrF;
    const unsigned k = (tid < SEQL) ? s_keys[tid] : 0u;
    const bool gt = (tid < SEQL) && (k > Tf);
    const bool eq = (tid < SEQL) && (k == Tf);
    const unsigned long long eb = __ballot(eq);
    if (lane == 0 && wave < 8) s_eqm[wave] = eb;
    __syncthreads();

    auto prefix8 = [&](const unsigned long long* w8, int pos) -> int {
        const int wi = pos >> 6;
        const unsigned long long lowmask = (1ull << (pos & 63)) - 1ull;
        int r = 0;
        #pragma unroll
        for (int q2 = 0; q2 < 8; ++q2) {
            const unsigned long long w = w8[q2];
            r += (q2 < wi) ? __popcll(w) : ((q2 == wi) ? __popcll(w & lowmask) : 0);
        }
        return r;
    };

    int f = 0;
    if (tid < SEQL) f = gt || (eq && prefix8(s_eqm, tid) < KrF);
    const unsigned long long fb = __ballot(f);
    if (lane == 0 && wave < 8) s_ind[wave] = fb;
    __syncthreads();
    if (tid < SEQL) s_c2m[tid] = prefix8(s_ind, tid);
    __syncthreads();

    // ---- Phase 3+4 concurrent on disjoint waves
    if (wave >= 12) {
        // bpm one-hot (4 waves = 256 threads), NT float4 stores
        const int sub = tid - 768;
        float* __restrict__ bpm = out + (size_t)BATCH * MORPH * HID + (size_t)b * (SEQL * MORPH);
        for (int v = sub; v < SEQL * MORPH / 4; v += 256) {
            const int l  = v / 6;
            const int qv = v - l * 6;
            const int c  = s_c2m[l];
            const int mb = qv * 4;
            const bool valid = (l < wl);
            f4v o;
            o.x = (valid && c == mb + 0 && mb + 0 < nm) ? 1.0f : 0.0f;
            o.y = (valid && c == mb + 1 && mb + 1 < nm) ? 1.0f : 0.0f;
            o.z = (valid && c == mb + 2 && mb + 2 < nm) ? 1.0f : 0.0f;
            o.w = (valid && c == mb + 3 && mb + 3 < nm) ? 1.0f : 0.0f;
            __builtin_nontemporal_store(o, reinterpret_cast<f4v*>(bpm) + v);
        }
    } else {
        // menc: 12 waves, contiguous row chunks, LDS-atomic flush on morpheme change
        const int start = (wave * wl) / 12;
        const int end   = ((wave + 1) * wl) / 12;
        float4 acc = {0.f, 0.f, 0.f, 0.f};
        int mcur = -1;
        for (int l = start; l < end; ++l) {
            const int mm = s_c2m[l];           // wave-uniform broadcast
            if (mm != mcur) {                  // wave-uniform branch
                if (mcur >= 0) {
                    atomicAdd(&s_acc[mcur][lane * 4 + 0], acc.x);
                    atomicAdd(&s_acc[mcur][lane * 4 + 1], acc.y);
                    atomicAdd(&s_acc[mcur][lane * 4 + 2], acc.z);
                    atomicAdd(&s_acc[mcur][lane * 4 + 3], acc.w);
                    acc.x = acc.y = acc.z = acc.w = 0.f;
                }
                mcur = mm;
            }
            const float4 v = reinterpret_cast<const float4*>(werow + (size_t)l * HID)[lane];
            acc.x += v.x; acc.y += v.y; acc.z += v.z; acc.w += v.w;
        }
        if (mcur >= 0) {
            atomicAdd(&s_acc[mcur][lane * 4 + 0], acc.x);
            atomicAdd(&s_acc[mcur][lane * 4 + 1], acc.y);
            atomicAdd(&s_acc[mcur][lane * 4 + 2], acc.z);
            atomicAdd(&s_acc[mcur][lane * 4 + 3], acc.w);
        }
    }
    __syncthreads();

    // ---- write menc (NT float4)
    {
        float* __restrict__ mout = out + (size_t)b * (MORPH * HID);
        const f4v* af = reinterpret_cast<const f4v*>(&s_acc[0][0]);
        for (int i = tid; i < MORPH * HID / 4; i += NTHR)
            __builtin_nontemporal_store(af[i], reinterpret_cast<f4v*>(mout) + i);
    }
}

extern "C" void kernel_launch(void* const* d_in, const int* in_sizes, int n_in,
                              void* d_out, int out_size, void* d_ws, size_t ws_size,
                              hipStream_t stream) {
    const float* we     = (const float*)d_in[0];
    const int*   wlen   = (const int*)d_in[1];
    const int*   nmorph = (const int*)d_in[2];
    const float* Wv     = (const float*)d_in[3];
    const float* bias   = (const float*)d_in[4];
    float* out = (float*)d_out;
    morphseg_kernel<<<dim3(BATCH), dim3(NTHR), 0, stream>>>(we, wlen, nmorph, Wv, bias, out);
}